// Round 4
// baseline (445.656 us; speedup 1.0000x reference)
//
#include <hip/hip_runtime.h>
#include <hip/hip_bf16.h>
#include <stdint.h>

// ---------- types ----------
typedef __attribute__((ext_vector_type(8))) short bf16x8;     // 8 bf16 (4 VGPRs) MFMA frag
typedef __attribute__((ext_vector_type(4))) float f32x4;      // MFMA accum
typedef __attribute__((ext_vector_type(4))) unsigned short u16x4;
typedef __attribute__((ext_vector_type(4))) float float4v;

#define MFMA16(a, b, c) __builtin_amdgcn_mfma_f32_16x16x32_bf16((a), (b), (c), 0, 0, 0)

// Native f32->bf16 (RTNE); pairs lower to v_cvt_pk_bf16_f32 on gfx950.
__device__ __forceinline__ unsigned short f2bf(float f) {
  return __builtin_bit_cast(unsigned short, (__bf16)f);
}
__device__ __forceinline__ float m3(float a, float b, float c) {
  return fmaxf(fmaxf(a, b), c);                 // clang fuses to v_max3_f32
}

typedef const __attribute__((address_space(1))) void* gptr1_t;
typedef __attribute__((address_space(3))) void* lptr3_t;
__device__ __forceinline__ void gload16(const void* g, void* l) {
  // HW semantics: LDS dest = wave-uniform base + lane*16; global src per-lane.
  __builtin_amdgcn_global_load_lds((gptr1_t)g, (lptr3_t)l, 16, 0, 0);
}

// ---------- 1) x fp32 -> bf16 ----------
__global__ __launch_bounds__(256) void cvt_x_kernel(const float* __restrict__ in,
                                                    unsigned short* __restrict__ out) {
  int i = blockIdx.x * 256 + threadIdx.x;          // exactly n/4 threads launched
  float4v f = ((const float4v*)in)[i];
  u16x4 o;
  o[0] = f2bf(f[0]); o[1] = f2bf(f[1]); o[2] = f2bf(f[2]); o[3] = f2bf(f[3]);
  ((u16x4*)out)[i] = o;
}

// ---------- 2) weight fp32 [K][N] -> bf16 transposed [N][K] ----------
__global__ __launch_bounds__(256) void wt_cvt_kernel(const float* __restrict__ w0,
                                                     const float* __restrict__ w1,
                                                     const float* __restrict__ w2,
                                                     const float* __restrict__ w3,
                                                     unsigned short* __restrict__ out) {
  const float* in = blockIdx.z == 0 ? w0 : blockIdx.z == 1 ? w1 : blockIdx.z == 2 ? w2 : w3;
  unsigned short* o = out + (size_t)blockIdx.z * 1024 * 1024;
  __shared__ float tile[32][33];
  int tx = threadIdx.x & 31, ty = threadIdx.x >> 5;          // 32 x 8
  int c0 = blockIdx.x * 32, r0 = blockIdx.y * 32;
#pragma unroll
  for (int i = 0; i < 4; i++)
    tile[ty + 8 * i][tx] = in[(size_t)(r0 + ty + 8 * i) * 1024 + c0 + tx];
  __syncthreads();
#pragma unroll
  for (int i = 0; i < 4; i++)
    o[(size_t)(c0 + ty + 8 * i) * 1024 + r0 + tx] = f2bf(tile[tx][ty + 8 * i]);
}

// ---------- 3) GEMM 128x128, BK=64 (m97 structure): C = A[M][1024](bf16) @ W ----------
template <bool OUTF32>
__global__ __launch_bounds__(256) void gemm128_kernel(
    const unsigned short* __restrict__ A,
    const unsigned short* __restrict__ B0, const unsigned short* __restrict__ B1,
    const unsigned short* __restrict__ B2,
    void* C0, void* C1, void* C2) {
  constexpr int K = 1024, N = 1024;
  const unsigned short* Bt = blockIdx.z == 0 ? B0 : blockIdx.z == 1 ? B1 : B2;
  void* Cv = blockIdx.z == 0 ? C0 : blockIdx.z == 1 ? C1 : C2;

  __shared__ unsigned short As[128 * 64];    // 16KB
  __shared__ unsigned short Bs[128 * 64];    // 16KB

  const int tid = threadIdx.x;
  const int w = tid >> 6, lane = tid & 63, l15 = lane & 15, l4 = lane >> 4;
  const int wm = w >> 1, wn = w & 1;
  const int m0 = blockIdx.x * 128, n0 = blockIdx.y * 128;

  f32x4 acc[4][4] = {};

  const int srow = w * 32 + (lane >> 3);     // staging row (inst i adds 8)
  const int scol = (lane & 7) * 8;           // bf16 col within BK=64
  const unsigned short* ga = A + (size_t)(m0 + srow) * K + scol;
  const unsigned short* gb = Bt + (size_t)(n0 + srow) * K + scol;
  char* lA = (char*)As + w * 4096;           // wave region 32 rows x 128B
  char* lB = (char*)Bs + w * 4096;

  for (int k0 = 0; k0 < K; k0 += 64) {
    __syncthreads();
#pragma unroll
    for (int i = 0; i < 4; i++) {
      gload16(ga + k0 + 8 * i * K, lA + i * 1024);
      gload16(gb + k0 + 8 * i * K, lB + i * 1024);
    }
    __syncthreads();

#pragma unroll
    for (int kk = 0; kk < 2; kk++) {
      bf16x8 af[4], bfr[4];
#pragma unroll
      for (int mi = 0; mi < 4; mi++)
        af[mi] = *(const bf16x8*)&As[(wm * 64 + mi * 16 + l15) * 64 + kk * 32 + 8 * l4];
#pragma unroll
      for (int ni = 0; ni < 4; ni++)
        bfr[ni] = *(const bf16x8*)&Bs[(wn * 64 + ni * 16 + l15) * 64 + kk * 32 + 8 * l4];
#pragma unroll
      for (int mi = 0; mi < 4; mi++)
#pragma unroll
        for (int ni = 0; ni < 4; ni++)
          acc[mi][ni] = MFMA16(af[mi], bfr[ni], acc[mi][ni]);
    }
  }

#pragma unroll
  for (int mi = 0; mi < 4; mi++)
#pragma unroll
    for (int ni = 0; ni < 4; ni++)
#pragma unroll
      for (int r = 0; r < 4; r++) {
        int mg = m0 + wm * 64 + mi * 16 + 4 * l4 + r;
        int ng = n0 + wn * 64 + ni * 16 + l15;
        if (OUTF32)
          ((float*)Cv)[(size_t)mg * N + ng] = acc[mi][ni][r];
        else
          ((unsigned short*)Cv)[(size_t)mg * N + ng] = f2bf(acc[mi][ni][r]);
      }
}

// ---------- 3b) GEMM 64x128 f32-out, BK=64: out-projection (1024 blocks = 4/CU) ----------
__global__ __launch_bounds__(256) void gemm64_kernel(const unsigned short* __restrict__ A,
                                                     const unsigned short* __restrict__ Bt,
                                                     float* __restrict__ Cv) {
  constexpr int K = 1024, N = 1024;
  __shared__ unsigned short As[64 * 64];     // 8KB
  __shared__ unsigned short Bs[128 * 64];    // 16KB

  const int tid = threadIdx.x;
  const int w = tid >> 6, lane = tid & 63, l15 = lane & 15, l4 = lane >> 4;
  const int wm = w >> 1, wn = w & 1;                // wave tile 32x64
  const int m0 = blockIdx.x * 64, n0 = blockIdx.y * 128;

  f32x4 acc[2][4] = {};

  const int arow = w * 16 + (lane >> 3);            // A staging: 16 rows/wave
  const int brow = w * 32 + (lane >> 3);            // B staging: 32 rows/wave
  const int scol = (lane & 7) * 8;
  const unsigned short* ga = A + (size_t)(m0 + arow) * K + scol;
  const unsigned short* gb = Bt + (size_t)(n0 + brow) * K + scol;
  char* lA = (char*)As + w * 2048;
  char* lB = (char*)Bs + w * 4096;

  for (int k0 = 0; k0 < K; k0 += 64) {
    __syncthreads();
#pragma unroll
    for (int i = 0; i < 2; i++)
      gload16(ga + k0 + 8 * i * K, lA + i * 1024);
#pragma unroll
    for (int i = 0; i < 4; i++)
      gload16(gb + k0 + 8 * i * K, lB + i * 1024);
    __syncthreads();

#pragma unroll
    for (int kk = 0; kk < 2; kk++) {
      bf16x8 af[2], bfr[4];
#pragma unroll
      for (int mi = 0; mi < 2; mi++)
        af[mi] = *(const bf16x8*)&As[(wm * 32 + mi * 16 + l15) * 64 + kk * 32 + 8 * l4];
#pragma unroll
      for (int ni = 0; ni < 4; ni++)
        bfr[ni] = *(const bf16x8*)&Bs[(wn * 64 + ni * 16 + l15) * 64 + kk * 32 + 8 * l4];
#pragma unroll
      for (int mi = 0; mi < 2; mi++)
#pragma unroll
        for (int ni = 0; ni < 4; ni++)
          acc[mi][ni] = MFMA16(af[mi], bfr[ni], acc[mi][ni]);
    }
  }

#pragma unroll
  for (int mi = 0; mi < 2; mi++)
#pragma unroll
    for (int ni = 0; ni < 4; ni++)
#pragma unroll
      for (int r = 0; r < 4; r++) {
        int mg = m0 + wm * 32 + mi * 16 + 4 * l4 + r;
        int ng = n0 + wn * 64 + ni * 16 + l15;
        Cv[(size_t)mg * N + ng] = acc[mi][ni][r];
      }
}

// ---------- 4) causal flash attention ----------
// Flat grid 1024, XCD-chunked decode (same-KV blocks -> same XCD L2; KV L2-resident,
// FETCH 24MB measured). Paired q-tiles qbA=p / qbB=31-p, uniform 33 tiles/block.
// This round: (1) row-sum l via ones-MFMA (l_acc rows == O rows; kills lt adds,
// lt shfls, epilogue shfls); (2) A/B stream interleave on shared tiles (indep work
// hides LDS/MFMA latency; same-wave DS ops are in-order so P region reuse is safe);
// (3) max-reduce as v_max3 tree. Defer-max (T13) unchanged.
__global__ __launch_bounds__(256, 4) void attn_kernel(const unsigned short* __restrict__ Qb,
                                                      const unsigned short* __restrict__ Kb,
                                                      const unsigned short* __restrict__ Vb,
                                                      unsigned short* __restrict__ Ob) {
  const int bid = blockIdx.x;
  const int xcd = bid & 7, slot = bid >> 3;       // round-robin dispatch: bid%8 = XCD
  const int hb = xcd * 8 + (slot >> 4);           // 8 (h,b) groups per XCD
  const int p = slot & 15;
  const int h = hb & 15, bb = hb >> 4;

  const int tid = threadIdx.x, w = tid >> 6, lane = tid & 63, l15 = lane & 15, l4 = lane >> 4;

  __shared__ unsigned short K_lds[2][64 * 64];    // [buf][kv][d], col-swizzled
  __shared__ unsigned short Vt_lds[2][64 * 64];   // [buf][d][kv], col-swizzled
  __shared__ unsigned short P_lds[4][16 * 64];    // per-wave [q][kv], col-swizzled

  const size_t brow = (size_t)bb * 2048;
  const int qq = w * 16 + l15;                    // in-tile q row (diag mask)
  const int sw = 8 * (l15 & 7);                   // K/P read swizzle (row&7 == l15&7)
  constexpr float C = 0.18033688f;                // 0.125 * log2(e)
  const bf16x8 ones = {0x3F80, 0x3F80, 0x3F80, 0x3F80, 0x3F80, 0x3F80, 0x3F80, 0x3F80};

  const int qbA = p, qbB = 31 - p;
  const int lastB = qbB;

  bf16x8 qfA0, qfA1, qfB0, qfB1;
  {
    const unsigned short* qa = Qb + (brow + qbA * 64 + qq) * 1024 + h * 64 + 8 * l4;
    qfA0 = *(const bf16x8*)qa;
    qfA1 = *(const bf16x8*)(qa + 32);
    const unsigned short* qbp = Qb + (brow + qbB * 64 + qq) * 1024 + h * 64 + 8 * l4;
    qfB0 = *(const bf16x8*)qbp;
    qfB1 = *(const bf16x8*)(qbp + 32);
  }

  f32x4 oA[4] = {}, oB[4] = {};
  f32x4 lA4 = {0.f, 0.f, 0.f, 0.f}, lB4 = {0.f, 0.f, 0.f, 0.f};
  float mrA = -__builtin_inff(), mrB = -__builtin_inff();

  // K staging: DMA with pre-swizzled global source (m173 pattern).
  const int kcol = 8 * ((lane & 7) ^ ((lane >> 3) & 7));
  const unsigned short* gk = Kb + (brow + 8 * w + (lane >> 3)) * 1024 + h * 64 + kcol;
  // V staging: each thread loads kv rows (vr0, vr0+1), d-chunk vsc..+7.
  const int vr0 = 2 * (tid >> 3);                 // 0..62
  const int vsc = (tid & 7) * 8;
  const unsigned short* gv = Vb + (brow + vr0) * 1024 + h * 64 + vsc;

  auto vt_write = [&](int buf, const bf16x8& v0, const bf16x8& v1) {
#pragma unroll
    for (int j = 0; j < 8; j++) {
      const int d = vsc + j;
      const int msk = 8 * ((d ^ (d >> 3)) & 7);
      uint32_t pk = (uint32_t)(unsigned short)v0[j] |
                    ((uint32_t)(unsigned short)v1[j] << 16);
      *(uint32_t*)&Vt_lds[buf][d * 64 + (vr0 ^ msk)] = pk;
    }
  };

  auto qk8 = [&](const unsigned short* Kc, const bf16x8& q0f, const bf16x8& q1f, f32x4* s) {
#pragma unroll
    for (int sub = 0; sub < 4; ++sub) {
      const unsigned short* kr0 = &Kc[(sub * 16 + l15) * 64 + ((8 * l4) ^ sw)];
      const unsigned short* kr1 = &Kc[(sub * 16 + l15) * 64 + ((32 + 8 * l4) ^ sw)];
      f32x4 z = {0.f, 0.f, 0.f, 0.f};
      z = MFMA16(*(const bf16x8*)kr0, q0f, z);
      z = MFMA16(*(const bf16x8*)kr1, q1f, z);
      s[sub] = z;
    }
  };

  // mask (diag only) + max3-tree reduce + defer-max rescale of O and l.
  auto maskmax = [&](f32x4* s, float& m_run, f32x4* oacc, f32x4& lacc, bool diag) {
    if (diag) {
#pragma unroll
      for (int sub = 0; sub < 4; ++sub)
#pragma unroll
        for (int r4 = 0; r4 < 4; r4++) {
          const int kv_t = sub * 16 + 4 * l4 + r4;
          s[sub][r4] = (kv_t > qq) ? -__builtin_inff() : s[sub][r4];
        }
    }
    const float t0 = m3(s[0][0], s[0][1], s[0][2]);
    const float t1 = m3(s[0][3], s[1][0], s[1][1]);
    const float t2 = m3(s[1][2], s[1][3], s[2][0]);
    const float t3 = m3(s[2][1], s[2][2], s[2][3]);
    const float t4 = m3(s[3][0], s[3][1], s[3][2]);
    float mt = fmaxf(m3(t0, t1, t2), m3(t3, t4, s[3][3]));
    mt = fmaxf(mt, __shfl_xor(mt, 16));
    mt = fmaxf(mt, __shfl_xor(mt, 32));
    if (!__all(mt <= m_run + 44.3614f)) {         // 44.3614 = 8 / C
      const float m_new = fmaxf(m_run, mt);
      const float alpha = __builtin_amdgcn_exp2f((m_run - m_new) * C);
      const float ao0 = __shfl(alpha, 4 * l4 + 0);
      const float ao1 = __shfl(alpha, 4 * l4 + 1);
      const float ao2 = __shfl(alpha, 4 * l4 + 2);
      const float ao3 = __shfl(alpha, 4 * l4 + 3);
#pragma unroll
      for (int d = 0; d < 4; ++d) {
        oacc[d][0] *= ao0; oacc[d][1] *= ao1; oacc[d][2] *= ao2; oacc[d][3] *= ao3;
      }
      lacc[0] *= ao0; lacc[1] *= ao1; lacc[2] *= ao2; lacc[3] *= ao3;
      m_run = m_new;
    }
  };

  auto expcvt = [&](const f32x4* s, float m_run, u16x4* pw) {
    const float mnc = m_run * C;
#pragma unroll
    for (int sub = 0; sub < 4; ++sub)
#pragma unroll
      for (int r4 = 0; r4 < 4; r4++)
        pw[sub][r4] = f2bf(__builtin_amdgcn_exp2f(__builtin_fmaf(s[sub][r4], C, -mnc)));
  };

  auto pstore = [&](const u16x4* pw) {
#pragma unroll
    for (int sub = 0; sub < 4; ++sub)
      *(u16x4*)&P_lds[w][l15 * 64 + ((sub * 16 + 4 * l4) ^ sw)] = pw[sub];
  };

  auto pload = [&](bf16x8& p0, bf16x8& p1) {
    p0 = *(const bf16x8*)&P_lds[w][l15 * 64 + ((8 * l4) ^ sw)];
    p1 = *(const bf16x8*)&P_lds[w][l15 * 64 + ((32 + 8 * l4) ^ sw)];
  };

  auto pv8 = [&](const unsigned short* Vtc, const bf16x8& p0, const bf16x8& p1, f32x4* oacc) {
#pragma unroll
    for (int d = 0; d < 4; ++d) {
      const int dd = d * 16 + l15;
      const int vm = 8 * ((dd ^ (dd >> 3)) & 7);
      const unsigned short* vp0 = &Vtc[dd * 64 + ((8 * l4) ^ vm)];
      const unsigned short* vp1 = &Vtc[dd * 64 + ((32 + 8 * l4) ^ vm)];
      oacc[d] = MFMA16(p0, *(const bf16x8*)vp0, oacc[d]);
      oacc[d] = MFMA16(p1, *(const bf16x8*)vp1, oacc[d]);
    }
  };

  // ---- prologue: stage tile 0 into buf 0 ----
  gload16(gk, (char*)K_lds[0] + w * 1024);
  gload16(gk + 32 * 1024, (char*)K_lds[0] + w * 1024 + 4096);
  {
    bf16x8 v0 = *(const bf16x8*)gv;
    bf16x8 v1 = *(const bf16x8*)(gv + 1024);
    vt_write(0, v0, v1);
  }
  __syncthreads();

  // ---- main loop: one barrier per KV tile ----
  for (int kb = 0; kb <= lastB; ++kb) {
    const int cur = kb & 1, nxt = cur ^ 1;
    const bool pre = kb < lastB;
    const unsigned short* Kc = K_lds[cur];
    const unsigned short* Vtc = Vt_lds[cur];
    bf16x8 pv0, pv1;
    if (pre) {
      const size_t off = (size_t)(kb + 1) * 64 * 1024;
      gload16(gk + off, (char*)K_lds[nxt] + w * 1024);
      gload16(gk + off + 32 * 1024, (char*)K_lds[nxt] + w * 1024 + 4096);
      pv0 = *(const bf16x8*)(gv + off);
      pv1 = *(const bf16x8*)(gv + off + 1024);
    }

    if (kb <= qbA) {
      // --- dual-stream interleaved tile ---
      f32x4 sA[4], sB[4];
      __builtin_amdgcn_s_setprio(1);
      qk8(Kc, qfA0, qfA1, sA);
      qk8(Kc, qfB0, qfB1, sB);
      __builtin_amdgcn_s_setprio(0);

      u16x4 pwA[4], pwB[4];
      maskmax(sA, mrA, oA, lA4, kb == qbA);
      expcvt(sA, mrA, pwA);
      pstore(pwA);
      maskmax(sB, mrB, oB, lB4, false);           // qbB==lastB handled below; kb<=qbA<lastB
      expcvt(sB, mrB, pwB);

      bf16x8 pA0, pA1;
      pload(pA0, pA1);
      __builtin_amdgcn_s_setprio(1);
      pv8(Vtc, pA0, pA1, oA);
      __builtin_amdgcn_s_setprio(0);
      pstore(pwB);                                 // after PV_A reads (same-wave DS in order)
      lA4 = MFMA16(pA0, ones, lA4);
      lA4 = MFMA16(pA1, ones, lA4);
      bf16x8 pB0, pB1;
      pload(pB0, pB1);
      __builtin_amdgcn_s_setprio(1);
      pv8(Vtc, pB0, pB1, oB);
      lB4 = MFMA16(pB0, ones, lB4);
      lB4 = MFMA16(pB1, ones, lB4);
      __builtin_amdgcn_s_setprio(0);
    } else {
      // --- single stream (B) ---
      f32x4 sB[4];
      __builtin_amdgcn_s_setprio(1);
      qk8(Kc, qfB0, qfB1, sB);
      __builtin_amdgcn_s_setprio(0);
      u16x4 pwB[4];
      maskmax(sB, mrB, oB, lB4, kb == lastB);
      expcvt(sB, mrB, pwB);
      pstore(pwB);
      bf16x8 pB0, pB1;
      pload(pB0, pB1);
      __builtin_amdgcn_s_setprio(1);
      pv8(Vtc, pB0, pB1, oB);
      lB4 = MFMA16(pB0, ones, lB4);
      lB4 = MFMA16(pB1, ones, lB4);
      __builtin_amdgcn_s_setprio(0);
    }

    if (pre) vt_write(nxt, pv0, pv1);
    __syncthreads();
  }

  // ---- epilogue: normalize + store both q-tiles (l rows == O rows, no shfl) ----
  {
    const float li[4] = {1.0f / lA4[0], 1.0f / lA4[1], 1.0f / lA4[2], 1.0f / lA4[3]};
#pragma unroll
    for (int d = 0; d < 4; ++d)
#pragma unroll
      for (int r4 = 0; r4 < 4; r4++) {
        const size_t orow = brow + qbA * 64 + w * 16 + 4 * l4 + r4;
        Ob[orow * 1024 + h * 64 + d * 16 + l15] = f2bf(oA[d][r4] * li[r4]);
      }
  }
  {
    const float li[4] = {1.0f / lB4[0], 1.0f / lB4[1], 1.0f / lB4[2], 1.0f / lB4[3]};
#pragma unroll
    for (int d = 0; d < 4; ++d)
#pragma unroll
      for (int r4 = 0; r4 < 4; r4++) {
        const size_t orow = brow + qbB * 64 + w * 16 + 4 * l4 + r4;
        Ob[orow * 1024 + h * 64 + d * 16 + l15] = f2bf(oB[d][r4] * li[r4]);
      }
  }
}

// ---------- launch ----------
extern "C" void kernel_launch(void* const* d_in, const int* in_sizes, int n_in,
                              void* d_out, int out_size, void* d_ws, size_t ws_size,
                              hipStream_t stream) {
  const float* x  = (const float*)d_in[0];
  const float* wq = (const float*)d_in[1];
  const float* wk = (const float*)d_in[2];
  const float* wv = (const float*)d_in[3];
  const float* wo = (const float*)d_in[4];

  char* ws = (char*)d_ws;
  // layout (bytes): Xb 16MB | Wt 4x2MB | Q 16MB | K 16MB | V 16MB ; O aliases Xb
  unsigned short* Xb  = (unsigned short*)(ws);
  unsigned short* Wt  = (unsigned short*)(ws + (16u << 20));
  unsigned short* Wqt = Wt;
  unsigned short* Wkt = Wt + (1u << 20);
  unsigned short* Wvt = Wt + (2u << 20);
  unsigned short* Wot = Wt + (3u << 20);
  unsigned short* Qb  = (unsigned short*)(ws + (24u << 20));
  unsigned short* Kb  = (unsigned short*)(ws + (40u << 20));
  unsigned short* Vb  = (unsigned short*)(ws + (56u << 20));
  unsigned short* Ob  = Xb;   // X no longer needed after QKV projection

  cvt_x_kernel<<<8192, 256, 0, stream>>>(x, Xb);                       // 8192*1024 f32 -> bf16
  wt_cvt_kernel<<<dim3(32, 32, 4), 256, 0, stream>>>(wq, wk, wv, wo, Wt);
  gemm128_kernel<false><<<dim3(64, 8, 3), 256, 0, stream>>>(Xb, Wqt, Wkt, Wvt, Qb, Kb, Vb);
  attn_kernel<<<1024, 256, 0, stream>>>(Qb, Kb, Vb, Ob);
  gemm64_kernel<<<dim3(128, 8), 256, 0, stream>>>(Ob, Wot, (float*)d_out);
}

// Round 5
// 173.894 us; speedup vs baseline: 2.5628x; 2.5628x over previous
//
#include <hip/hip_runtime.h>
#include <hip/hip_bf16.h>
#include <stdint.h>

// ---------- types ----------
typedef __attribute__((ext_vector_type(8))) short bf16x8;     // 8 bf16 (4 VGPRs) MFMA frag
typedef __attribute__((ext_vector_type(4))) float f32x4;      // MFMA accum
typedef __attribute__((ext_vector_type(4))) unsigned short u16x4;
typedef __attribute__((ext_vector_type(4))) float float4v;

#define MFMA16(a, b, c) __builtin_amdgcn_mfma_f32_16x16x32_bf16((a), (b), (c), 0, 0, 0)

// Native f32->bf16 (RTNE); pairs lower to v_cvt_pk_bf16_f32 on gfx950.
__device__ __forceinline__ unsigned short f2bf(float f) {
  return __builtin_bit_cast(unsigned short, (__bf16)f);
}
__device__ __forceinline__ float m3(float a, float b, float c) {
  return fmaxf(fmaxf(a, b), c);                 // clang fuses to v_max3_f32
}

typedef const __attribute__((address_space(1))) void* gptr1_t;
typedef __attribute__((address_space(3))) void* lptr3_t;
__device__ __forceinline__ void gload16(const void* g, void* l) {
  // HW semantics: LDS dest = wave-uniform base + lane*16; global src per-lane.
  __builtin_amdgcn_global_load_lds((gptr1_t)g, (lptr3_t)l, 16, 0, 0);
}

// ---------- 1) x fp32 -> bf16 ----------
__global__ __launch_bounds__(256) void cvt_x_kernel(const float* __restrict__ in,
                                                    unsigned short* __restrict__ out) {
  int i = blockIdx.x * 256 + threadIdx.x;          // exactly n/4 threads launched
  float4v f = ((const float4v*)in)[i];
  u16x4 o;
  o[0] = f2bf(f[0]); o[1] = f2bf(f[1]); o[2] = f2bf(f[2]); o[3] = f2bf(f[3]);
  ((u16x4*)out)[i] = o;
}

// ---------- 2) weight fp32 [K][N] -> bf16 transposed [N][K] ----------
__global__ __launch_bounds__(256) void wt_cvt_kernel(const float* __restrict__ w0,
                                                     const float* __restrict__ w1,
                                                     const float* __restrict__ w2,
                                                     const float* __restrict__ w3,
                                                     unsigned short* __restrict__ out) {
  const float* in = blockIdx.z == 0 ? w0 : blockIdx.z == 1 ? w1 : blockIdx.z == 2 ? w2 : w3;
  unsigned short* o = out + (size_t)blockIdx.z * 1024 * 1024;
  __shared__ float tile[32][33];
  int tx = threadIdx.x & 31, ty = threadIdx.x >> 5;          // 32 x 8
  int c0 = blockIdx.x * 32, r0 = blockIdx.y * 32;
#pragma unroll
  for (int i = 0; i < 4; i++)
    tile[ty + 8 * i][tx] = in[(size_t)(r0 + ty + 8 * i) * 1024 + c0 + tx];
  __syncthreads();
#pragma unroll
  for (int i = 0; i < 4; i++)
    o[(size_t)(c0 + ty + 8 * i) * 1024 + r0 + tx] = f2bf(tile[tx][ty + 8 * i]);
}

// ---------- 3) GEMM 128x128, BK=32 (m97 structure): C = A[M][1024](bf16) @ W ----------
template <bool OUTF32>
__global__ __launch_bounds__(256) void gemm128_kernel(
    const unsigned short* __restrict__ A,
    const unsigned short* __restrict__ B0, const unsigned short* __restrict__ B1,
    const unsigned short* __restrict__ B2,
    void* C0, void* C1, void* C2) {
  constexpr int K = 1024, N = 1024;
  const unsigned short* Bt = blockIdx.z == 0 ? B0 : blockIdx.z == 1 ? B1 : B2;
  void* Cv = blockIdx.z == 0 ? C0 : blockIdx.z == 1 ? C1 : C2;

  __shared__ unsigned short As[128 * 32];
  __shared__ unsigned short Bs[128 * 32];

  const int tid = threadIdx.x;
  const int w = tid >> 6, lane = tid & 63, l15 = lane & 15, l4 = lane >> 4;
  const int wm = w >> 1, wn = w & 1;
  const int m0 = blockIdx.x * 128, n0 = blockIdx.y * 128;

  f32x4 acc[4][4] = {};

  const int srow = w * 32 + (lane >> 2);     // staging row (inst i adds 16)
  const int scol = (lane & 3) * 8;           // bf16 col within BK
  const unsigned short* ga = A + (size_t)(m0 + srow) * K + scol;
  const unsigned short* gb = Bt + (size_t)(n0 + srow) * K + scol;
  char* lA = (char*)As + w * 2048;           // + i*1024 ; HW adds lane*16
  char* lB = (char*)Bs + w * 2048;

  for (int k0 = 0; k0 < K; k0 += 32) {
    __syncthreads();
    gload16(ga + k0, lA);
    gload16(ga + k0 + 16 * K, lA + 1024);
    gload16(gb + k0, lB);
    gload16(gb + k0 + 16 * K, lB + 1024);
    __syncthreads();

    bf16x8 af[4], bfr[4];
#pragma unroll
    for (int mi = 0; mi < 4; mi++)
      af[mi] = *(const bf16x8*)&As[(wm * 64 + mi * 16 + l15) * 32 + 8 * l4];
#pragma unroll
    for (int ni = 0; ni < 4; ni++)
      bfr[ni] = *(const bf16x8*)&Bs[(wn * 64 + ni * 16 + l15) * 32 + 8 * l4];
#pragma unroll
    for (int mi = 0; mi < 4; mi++)
#pragma unroll
      for (int ni = 0; ni < 4; ni++)
        acc[mi][ni] = MFMA16(af[mi], bfr[ni], acc[mi][ni]);
  }

#pragma unroll
  for (int mi = 0; mi < 4; mi++)
#pragma unroll
    for (int ni = 0; ni < 4; ni++)
#pragma unroll
      for (int r = 0; r < 4; r++) {
        int mg = m0 + wm * 64 + mi * 16 + 4 * l4 + r;
        int ng = n0 + wn * 64 + ni * 16 + l15;
        if (OUTF32)
          ((float*)Cv)[(size_t)mg * N + ng] = acc[mi][ni][r];
        else
          ((unsigned short*)Cv)[(size_t)mg * N + ng] = f2bf(acc[mi][ni][r]);
      }
}

// ---------- 3b) GEMM 64x128 f32-out: out-projection (1024 blocks = 4/CU) ----------
__global__ __launch_bounds__(256) void gemm64_kernel(const unsigned short* __restrict__ A,
                                                     const unsigned short* __restrict__ Bt,
                                                     float* __restrict__ Cv) {
  constexpr int K = 1024, N = 1024;
  __shared__ unsigned short As[64 * 32];
  __shared__ unsigned short Bs[128 * 32];

  const int tid = threadIdx.x;
  const int w = tid >> 6, lane = tid & 63, l15 = lane & 15, l4 = lane >> 4;
  const int wm = w >> 1, wn = w & 1;                // wave tile 32x64
  const int m0 = blockIdx.x * 64, n0 = blockIdx.y * 128;

  f32x4 acc[2][4] = {};

  const int arow = w * 16 + (lane >> 2);            // A staging: 16 rows/wave
  const int brow = w * 32 + (lane >> 2);            // B staging: 32 rows/wave (2 insts)
  const int scol = (lane & 3) * 8;
  const unsigned short* ga = A + (size_t)(m0 + arow) * K + scol;
  const unsigned short* gb = Bt + (size_t)(n0 + brow) * K + scol;
  char* lA = (char*)As + w * 1024;
  char* lB = (char*)Bs + w * 2048;

  for (int k0 = 0; k0 < K; k0 += 32) {
    __syncthreads();
    gload16(ga + k0, lA);
    gload16(gb + k0, lB);
    gload16(gb + k0 + 16 * K, lB + 1024);
    __syncthreads();

    bf16x8 af[2], bfr[4];
#pragma unroll
    for (int mi = 0; mi < 2; mi++)
      af[mi] = *(const bf16x8*)&As[(wm * 32 + mi * 16 + l15) * 32 + 8 * l4];
#pragma unroll
    for (int ni = 0; ni < 4; ni++)
      bfr[ni] = *(const bf16x8*)&Bs[(wn * 64 + ni * 16 + l15) * 32 + 8 * l4];
#pragma unroll
    for (int mi = 0; mi < 2; mi++)
#pragma unroll
      for (int ni = 0; ni < 4; ni++)
        acc[mi][ni] = MFMA16(af[mi], bfr[ni], acc[mi][ni]);
  }

#pragma unroll
  for (int mi = 0; mi < 2; mi++)
#pragma unroll
    for (int ni = 0; ni < 4; ni++)
#pragma unroll
      for (int r = 0; r < 4; r++) {
        int mg = m0 + wm * 32 + mi * 16 + 4 * l4 + r;
        int ng = n0 + wn * 64 + ni * 16 + l15;
        Cv[(size_t)mg * N + ng] = acc[mi][ni][r];
      }
}

// ---------- 4) causal flash attention ----------
// Round-3 structure (verified 78us, 64 VGPR, no spill) + register-light grafts from R4:
//   - l row-sum via ones-MFMA: lacc rows == O rows; kills lt adds, 2 lt shfls/tile,
//     and all 8 epilogue shfls. (+8 VGPR only.)
//   - max-reduce as v_max3 tree (shorter serial chain).
// NO dual-stream interleave (R4: spilled to scratch, 550MB scratch writes).
// Flat grid 1024, XCD-chunked decode (same-KV blocks -> same XCD L2; KV L2-resident).
// Paired q-tiles qbA=p / qbB=31-p; double-buffered K/Vt; ONE barrier per KV tile;
// next-tile K via global_load_lds (pre-swizzled src) + V reg-staged before compute.
__global__ __launch_bounds__(256, 4) void attn_kernel(const unsigned short* __restrict__ Qb,
                                                      const unsigned short* __restrict__ Kb,
                                                      const unsigned short* __restrict__ Vb,
                                                      unsigned short* __restrict__ Ob) {
  const int bid = blockIdx.x;
  const int xcd = bid & 7, slot = bid >> 3;       // round-robin dispatch: bid%8 = XCD
  const int hb = xcd * 8 + (slot >> 4);           // 8 (h,b) groups per XCD
  const int p = slot & 15;
  const int h = hb & 15, bb = hb >> 4;

  const int tid = threadIdx.x, w = tid >> 6, lane = tid & 63, l15 = lane & 15, l4 = lane >> 4;

  __shared__ unsigned short K_lds[2][64 * 64];    // [buf][kv][d], col-swizzled
  __shared__ unsigned short Vt_lds[2][64 * 64];   // [buf][d][kv], col-swizzled
  __shared__ unsigned short P_lds[4][16 * 64];    // per-wave [q][kv], col-swizzled

  const size_t brow = (size_t)bb * 2048;
  const int qq = w * 16 + l15;                    // in-tile q row (diag mask)
  const int sw = 8 * (l15 & 7);                   // K/P read swizzle (row&7 == l15&7)
  constexpr float C = 0.18033688f;                // 0.125 * log2(e)
  const bf16x8 ones = {0x3F80, 0x3F80, 0x3F80, 0x3F80, 0x3F80, 0x3F80, 0x3F80, 0x3F80};

  const int qbA = p, qbB = 31 - p;
  const int lastB = qbB;

  bf16x8 qfA0, qfA1, qfB0, qfB1;
  {
    const unsigned short* qa = Qb + (brow + qbA * 64 + qq) * 1024 + h * 64 + 8 * l4;
    qfA0 = *(const bf16x8*)qa;
    qfA1 = *(const bf16x8*)(qa + 32);
    const unsigned short* qbp = Qb + (brow + qbB * 64 + qq) * 1024 + h * 64 + 8 * l4;
    qfB0 = *(const bf16x8*)qbp;
    qfB1 = *(const bf16x8*)(qbp + 32);
  }

  f32x4 oA[4] = {}, oB[4] = {};
  f32x4 lA4 = {0.f, 0.f, 0.f, 0.f}, lB4 = {0.f, 0.f, 0.f, 0.f};
  float mrA = -__builtin_inff(), mrB = -__builtin_inff();

  // K staging: DMA with pre-swizzled global source (m173 pattern).
  const int kcol = 8 * ((lane & 7) ^ ((lane >> 3) & 7));
  const unsigned short* gk = Kb + (brow + 8 * w + (lane >> 3)) * 1024 + h * 64 + kcol;
  // V staging: each thread loads kv rows (vr0, vr0+1), d-chunk vsc..+7.
  const int vr0 = 2 * (tid >> 3);                 // 0..62
  const int vsc = (tid & 7) * 8;
  const unsigned short* gv = Vb + (brow + vr0) * 1024 + h * 64 + vsc;

  auto vt_write = [&](int buf, const bf16x8& v0, const bf16x8& v1) {
#pragma unroll
    for (int j = 0; j < 8; j++) {
      const int d = vsc + j;
      const int msk = 8 * ((d ^ (d >> 3)) & 7);
      uint32_t pk = (uint32_t)(unsigned short)v0[j] |
                    ((uint32_t)(unsigned short)v1[j] << 16);
      *(uint32_t*)&Vt_lds[buf][d * 64 + (vr0 ^ msk)] = pk;
    }
  };

  auto tile_compute = [&](const unsigned short* Kc, const unsigned short* Vtc,
                          const bf16x8& q0f, const bf16x8& q1f, f32x4* oacc,
                          float& m_run, f32x4& lacc, bool diag) {
    // S^T = K x Q^T : 8 MFMA
    f32x4 s[4];
    __builtin_amdgcn_s_setprio(1);
#pragma unroll
    for (int sub = 0; sub < 4; ++sub) {
      const unsigned short* kr0 = &Kc[(sub * 16 + l15) * 64 + ((8 * l4) ^ sw)];
      const unsigned short* kr1 = &Kc[(sub * 16 + l15) * 64 + ((32 + 8 * l4) ^ sw)];
      f32x4 z = {0.f, 0.f, 0.f, 0.f};
      z = MFMA16(*(const bf16x8*)kr0, q0f, z);
      z = MFMA16(*(const bf16x8*)kr1, q1f, z);
      s[sub] = z;
    }
    __builtin_amdgcn_s_setprio(0);

    // causal mask only on the diagonal tile
    if (diag) {
#pragma unroll
      for (int sub = 0; sub < 4; ++sub)
#pragma unroll
        for (int r4 = 0; r4 < 4; r4++) {
          const int kv_t = sub * 16 + 4 * l4 + r4;
          s[sub][r4] = (kv_t > qq) ? -__builtin_inff() : s[sub][r4];
        }
    }
    // max3-tree reduce (16 -> 6 -> 2 -> 1), then cross-lane over l4 groups
    const float t0 = m3(s[0][0], s[0][1], s[0][2]);
    const float t1 = m3(s[0][3], s[1][0], s[1][1]);
    const float t2 = m3(s[1][2], s[1][3], s[2][0]);
    const float t3 = m3(s[2][1], s[2][2], s[2][3]);
    const float t4 = m3(s[3][0], s[3][1], s[3][2]);
    float mt = fmaxf(m3(t0, t1, t2), m3(t3, t4, s[3][3]));
    mt = fmaxf(mt, __shfl_xor(mt, 16));
    mt = fmaxf(mt, __shfl_xor(mt, 32));

    // defer-max: only rescale when some row grew by > 8 (log2 units) => P <= 2^8
    if (!__all(mt <= m_run + 44.3614f)) {         // 44.3614 = 8 / C
      const float m_new = fmaxf(m_run, mt);
      const float alpha = __builtin_amdgcn_exp2f((m_run - m_new) * C);
      const float ao0 = __shfl(alpha, 4 * l4 + 0);
      const float ao1 = __shfl(alpha, 4 * l4 + 1);
      const float ao2 = __shfl(alpha, 4 * l4 + 2);
      const float ao3 = __shfl(alpha, 4 * l4 + 3);
#pragma unroll
      for (int d = 0; d < 4; ++d) {
        oacc[d][0] *= ao0; oacc[d][1] *= ao1; oacc[d][2] *= ao2; oacc[d][3] *= ao3;
      }
      lacc[0] *= ao0; lacc[1] *= ao1; lacc[2] *= ao2; lacc[3] *= ao3;
      m_run = m_new;
    }
    const float mnc = m_run * C;

#pragma unroll
    for (int sub = 0; sub < 4; ++sub) {
      u16x4 pw;
#pragma unroll
      for (int r4 = 0; r4 < 4; r4++)
        pw[r4] = f2bf(__builtin_amdgcn_exp2f(__builtin_fmaf(s[sub][r4], C, -mnc)));
      *(u16x4*)&P_lds[w][l15 * 64 + ((sub * 16 + 4 * l4) ^ sw)] = pw;
    }

    // PV: O[q][d] += P[q][kv] V[kv][d]; l[q] += sum_kv P[q][kv] via ones-MFMA
    const bf16x8 pf0 = *(const bf16x8*)&P_lds[w][l15 * 64 + ((8 * l4) ^ sw)];
    const bf16x8 pf1 = *(const bf16x8*)&P_lds[w][l15 * 64 + ((32 + 8 * l4) ^ sw)];
    __builtin_amdgcn_s_setprio(1);
#pragma unroll
    for (int d = 0; d < 4; ++d) {
      const int dd = d * 16 + l15;
      const int vm = 8 * ((dd ^ (dd >> 3)) & 7);
      const unsigned short* vp0 = &Vtc[dd * 64 + ((8 * l4) ^ vm)];
      const unsigned short* vp1 = &Vtc[dd * 64 + ((32 + 8 * l4) ^ vm)];
      oacc[d] = MFMA16(pf0, *(const bf16x8*)vp0, oacc[d]);
      oacc[d] = MFMA16(pf1, *(const bf16x8*)vp1, oacc[d]);
    }
    lacc = MFMA16(pf0, ones, lacc);
    lacc = MFMA16(pf1, ones, lacc);
    __builtin_amdgcn_s_setprio(0);
  };

  // ---- prologue: stage tile 0 into buf 0 ----
  gload16(gk, (char*)K_lds[0] + w * 1024);
  gload16(gk + 32 * 1024, (char*)K_lds[0] + w * 1024 + 4096);
  {
    bf16x8 v0 = *(const bf16x8*)gv;
    bf16x8 v1 = *(const bf16x8*)(gv + 1024);
    vt_write(0, v0, v1);
  }
  __syncthreads();

  // ---- main loop: one barrier per KV tile ----
  for (int kb = 0; kb <= lastB; ++kb) {
    const int cur = kb & 1, nxt = cur ^ 1;
    const bool pre = kb < lastB;
    bf16x8 pv0, pv1;
    if (pre) {
      const size_t off = (size_t)(kb + 1) * 64 * 1024;
      gload16(gk + off, (char*)K_lds[nxt] + w * 1024);
      gload16(gk + off + 32 * 1024, (char*)K_lds[nxt] + w * 1024 + 4096);
      pv0 = *(const bf16x8*)(gv + off);
      pv1 = *(const bf16x8*)(gv + off + 1024);
    }

    if (kb <= qbA)
      tile_compute(K_lds[cur], Vt_lds[cur], qfA0, qfA1, oA, mrA, lA4, kb == qbA);
    tile_compute(K_lds[cur], Vt_lds[cur], qfB0, qfB1, oB, mrB, lB4, kb == lastB);

    if (pre) vt_write(nxt, pv0, pv1);
    __syncthreads();
  }

  // ---- epilogue: normalize + store both q-tiles (l rows == O rows, no shfl) ----
  {
    const float li[4] = {1.0f / lA4[0], 1.0f / lA4[1], 1.0f / lA4[2], 1.0f / lA4[3]};
#pragma unroll
    for (int d = 0; d < 4; ++d)
#pragma unroll
      for (int r4 = 0; r4 < 4; r4++) {
        const size_t orow = brow + qbA * 64 + w * 16 + 4 * l4 + r4;
        Ob[orow * 1024 + h * 64 + d * 16 + l15] = f2bf(oA[d][r4] * li[r4]);
      }
  }
  {
    const float li[4] = {1.0f / lB4[0], 1.0f / lB4[1], 1.0f / lB4[2], 1.0f / lB4[3]};
#pragma unroll
    for (int d = 0; d < 4; ++d)
#pragma unroll
      for (int r4 = 0; r4 < 4; r4++) {
        const size_t orow = brow + qbB * 64 + w * 16 + 4 * l4 + r4;
        Ob[orow * 1024 + h * 64 + d * 16 + l15] = f2bf(oB[d][r4] * li[r4]);
      }
  }
}

// ---------- launch ----------
extern "C" void kernel_launch(void* const* d_in, const int* in_sizes, int n_in,
                              void* d_out, int out_size, void* d_ws, size_t ws_size,
                              hipStream_t stream) {
  const float* x  = (const float*)d_in[0];
  const float* wq = (const float*)d_in[1];
  const float* wk = (const float*)d_in[2];
  const float* wv = (const float*)d_in[3];
  const float* wo = (const float*)d_in[4];

  char* ws = (char*)d_ws;
  // layout (bytes): Xb 16MB | Wt 4x2MB | Q 16MB | K 16MB | V 16MB ; O aliases Xb
  unsigned short* Xb  = (unsigned short*)(ws);
  unsigned short* Wt  = (unsigned short*)(ws + (16u << 20));
  unsigned short* Wqt = Wt;
  unsigned short* Wkt = Wt + (1u << 20);
  unsigned short* Wvt = Wt + (2u << 20);
  unsigned short* Wot = Wt + (3u << 20);
  unsigned short* Qb  = (unsigned short*)(ws + (24u << 20));
  unsigned short* Kb  = (unsigned short*)(ws + (40u << 20));
  unsigned short* Vb  = (unsigned short*)(ws + (56u << 20));
  unsigned short* Ob  = Xb;   // X no longer needed after QKV projection

  cvt_x_kernel<<<8192, 256, 0, stream>>>(x, Xb);                       // 8192*1024 f32 -> bf16
  wt_cvt_kernel<<<dim3(32, 32, 4), 256, 0, stream>>>(wq, wk, wv, wo, Wt);
  gemm128_kernel<false><<<dim3(64, 8, 3), 256, 0, stream>>>(Xb, Wqt, Wkt, Wvt, Qb, Kb, Vb);
  attn_kernel<<<1024, 256, 0, stream>>>(Qb, Kb, Vb, Ob);
  gemm64_kernel<<<dim3(128, 8), 256, 0, stream>>>(Ob, Wot, (float*)d_out);
}